// Round 3
// baseline (1852.650 us; speedup 1.0000x reference)
//
#include <hip/hip_runtime.h>

typedef float f32x2 __attribute__((ext_vector_type(2)));

#define TSTEPS 1000
#define BATCH  512
#define HID    64
#define INPD   64
#define FEAT   128
#define KEEP   5
#define KH     320
#define ALPHA  0.2f
#define BB     2
#define NBLK   (BATCH/BB)   // 256
#define NTHR   512

__device__ __forceinline__ float rdlane(float v, int l) {
  return __int_as_float(__builtin_amdgcn_readlane(__float_as_int(v), l));
}

// Single persistent kernel. 256 blocks (1/CU) x 8 waves, BB=2 batch/block.
// h lives in registers of EVERY wave (redundant finalize); ring of older h in LDS.
// Per step: [D(finalize h_{t-1}) + A(x/rnn/mlp1 partials)] | bar | C(relu+mlp2) | bar
__global__ __launch_bounds__(NTHR, 2) void seq_kernel(const float* __restrict__ x,
                                                      float* __restrict__ io,
                                                      const float* __restrict__ h0,
                                                      const float* __restrict__ W_in,
                                                      const float* __restrict__ b_in,
                                                      const float* __restrict__ W_hh,
                                                      const float* __restrict__ b_hh,
                                                      const float* __restrict__ W1,
                                                      const float* __restrict__ b1g,
                                                      const float* __restrict__ W2,
                                                      const float* __restrict__ b2g) {
  __shared__ float pA[8*128*2];      // [w][f][b] mlp1 partials (single buffer)
  __shared__ float pR[2][8*64*2];    // [parity][w][h][b] rnn+x partials
  __shared__ float pR2[8*64*2];      // [w][h][b] mlp2 partials
  __shared__ float bufT[KEEP*64*2];  // [slot][j][b] ring; slot m%5 holds h_m

  const int tid  = threadIdx.x;
  const int w    = tid >> 6;
  const int lane = tid & 63;
  const int b0   = blockIdx.x * BB;

  // ---- weight registers ----
  // MLP1: wave w owns j(i) = 64*(i%5) + 8*(i/5) + w, i=0..39; lane owns f-pair (lane, lane+64)
  f32x2 w1p[40];
#pragma unroll
  for (int i = 0; i < 40; ++i) {
    const int j = 64*(i%5) + 8*(i/5) + w;
    w1p[i].x = W1[(size_t)lane*KH + j];
    w1p[i].y = W1[(size_t)(lane+64)*KH + j];
  }
  float whr[8], winr[8];
#pragma unroll
  for (int jj = 0; jj < 8; ++jj) {
    whr[jj]  = W_hh[lane*HID  + 8*w + jj];
    winr[jj] = W_in[lane*INPD + 8*w + jj];
  }
  float w2r[16];
#pragma unroll
  for (int ff = 0; ff < 16; ++ff) w2r[ff] = W2[lane*FEAT + 16*w + ff];

  const float biasv = b_in[lane] + b_hh[lane];
  const float b2v   = b2g[lane];
  const float b1v   = (lane < 16) ? b1g[16*w + lane] : 0.f;

  // per-lane MLP1 gather constants (lane<40): lane i holds ring value for j(i)
  const int kc   = lane % 5;
  const int joff = 8*(lane/5) + w;

  // ---- state ----
  f32x2 hn;                       // h_{t-1}, identical in all waves
  hn.x = h0[b0*HID + lane];
  hn.y = h0[(b0+1)*HID + lane];

  for (int i2 = tid; i2 < KEEP*128; i2 += NTHR) bufT[i2] = 0.f;

  f32x2 xc; xc.x = 0.f; xc.y = 0.f;          // x[t] slice for this wave (lanes 0..7)
  if (lane < 8) {
    xc.x = x[(size_t)0*BATCH*INPD + (b0+0)*INPD + 8*w + lane];
    xc.y = x[(size_t)0*BATCH*INPD + (b0+1)*INPD + 8*w + lane];
  }
  __syncthreads();

  // D: finalize h_{t-1} from step-(t-1) partials; all waves redundantly.
  auto doD = [&](int t, int s5, bool last) {
    const int pr = (t-1) & 1;
    f32x2 sr; sr.x = biasv; sr.y = biasv;
    f32x2 sm; sm.x = b2v;   sm.y = b2v;
#pragma unroll
    for (int ww = 0; ww < 8; ++ww) {
      sr += *(const f32x2*)(&pR[pr][ww*128 + lane*2]);
      sm += *(const f32x2*)(&pR2[ww*128 + lane*2]);
    }
    f32x2 z; z.x = 0.f; z.y = 0.f;
    f32x2 rl = __builtin_elementwise_max(sr, z);
    f32x2 hobs = hn*(1.f-ALPHA) + rl*ALPHA;
    if (t-1 >= KEEP) hn = (hobs + sm)*0.5f; else hn = hobs;
    if (w == 0) {
      if (!last) {
        int sw = s5 + 4; if (sw >= KEEP) sw -= KEEP;    // slot (t-1)%5
        *(f32x2*)(&bufT[sw*128 + lane*2]) = hn;
      }
      io[(size_t)(t-1)*BATCH*HID + (b0+0)*HID + lane] = hn.x;
      io[(size_t)(t-1)*BATCH*HID + (b0+1)*HID + lane] = hn.y;
      if (last) {
        io[(size_t)TSTEPS*BATCH*HID + (b0+0)*HID + lane] = hn.x;
        io[(size_t)TSTEPS*BATCH*HID + (b0+1)*HID + lane] = hn.y;
      }
    }
  };

  int s5 = 0;   // t % 5
  for (int t = 0; t < TSTEPS; ++t) {
    // issue ring read early (old slots only; newest comes from hn registers)
    f32x2 bv; bv.x = 0.f; bv.y = 0.f;
    if (lane < 40 && kc < 4) {
      int sl = s5 + kc; if (sl >= KEEP) sl -= KEEP;
      bv = *(const f32x2*)(&bufT[sl*128 + joff*2]);
    }

    if (t > 0) doD(t, s5, false);

    // prefetch x for step t+1
    f32x2 xn; xn.x = 0.f; xn.y = 0.f;
    if (t+1 < TSTEPS && lane < 8) {
      xn.x = x[(size_t)(t+1)*BATCH*INPD + (b0+0)*INPD + 8*w + lane];
      xn.y = x[(size_t)(t+1)*BATCH*INPD + (b0+1)*INPD + 8*w + lane];
    }

    // ---- A: rnn + x partials (h_{t-1} and x_t broadcast from registers) ----
    float r0 = 0.f, r1 = 0.f;
#pragma unroll
    for (int jj = 0; jj < 8; ++jj) {
      r0 = fmaf(whr[jj], rdlane(hn.x, 8*w + jj), r0);
      r1 = fmaf(whr[jj], rdlane(hn.y, 8*w + jj), r1);
    }
#pragma unroll
    for (int jj = 0; jj < 8; ++jj) {
      r0 = fmaf(winr[jj], rdlane(xc.x, jj), r0);
      r1 = fmaf(winr[jj], rdlane(xc.y, jj), r1);
    }
    *(f32x2*)(&pR[t & 1][w*128 + lane*2]) = f32x2{r0, r1};

    // ---- A: mlp1 partials, packed over f-pair ----
    f32x2 a0; a0.x = 0.f; a0.y = 0.f;   // batch b0, f in {lane, lane+64}
    f32x2 a1; a1.x = 0.f; a1.y = 0.f;   // batch b1
#pragma unroll
    for (int i = 0; i < 40; ++i) {
      float s0, s1;
      if ((i % 5) == 4) {               // newest slot: from registers
        s0 = rdlane(hn.x, 8*(i/5) + w);
        s1 = rdlane(hn.y, 8*(i/5) + w);
      } else {                          // older slots: from ring value held at lane i
        s0 = rdlane(bv.x, i);
        s1 = rdlane(bv.y, i);
      }
      f32x2 sv0; sv0.x = s0; sv0.y = s0;
      f32x2 sv1; sv1.x = s1; sv1.y = s1;
      a0 = __builtin_elementwise_fma(w1p[i], sv0, a0);
      a1 = __builtin_elementwise_fma(w1p[i], sv1, a1);
    }
    *(f32x2*)(&pA[w*256 + lane*2])       = f32x2{a0.x, a1.x};  // f = lane
    *(f32x2*)(&pA[w*256 + 128 + lane*2]) = f32x2{a0.y, a1.y};  // f = lane+64
    __syncthreads();

    // ---- C: reduce mlp1 slice + relu, then mlp2 partials ----
    float aR0 = 0.f, aR1 = 0.f;
    if (lane < 16) {
      const int f = 16*w + lane;
      f32x2 s; s.x = b1v; s.y = b1v;
#pragma unroll
      for (int ww = 0; ww < 8; ++ww) s += *(const f32x2*)(&pA[ww*256 + f*2]);
      f32x2 z; z.x = 0.f; z.y = 0.f;
      s = __builtin_elementwise_max(s, z);
      aR0 = s.x; aR1 = s.y;
    }
    float c0 = 0.f, c1 = 0.f;
#pragma unroll
    for (int ff = 0; ff < 16; ++ff) {
      c0 = fmaf(w2r[ff], rdlane(aR0, ff), c0);
      c1 = fmaf(w2r[ff], rdlane(aR1, ff), c1);
    }
    *(f32x2*)(&pR2[w*128 + lane*2]) = f32x2{c0, c1};
    __syncthreads();

    xc = xn;
    s5 = (s5 == KEEP-1) ? 0 : s5 + 1;
  }

  doD(TSTEPS, s5, true);
}

extern "C" void kernel_launch(void* const* d_in, const int* in_sizes, int n_in,
                              void* d_out, int out_size, void* d_ws, size_t ws_size,
                              hipStream_t stream) {
  (void)in_sizes; (void)n_in; (void)out_size; (void)d_ws; (void)ws_size;
  const float* x    = (const float*)d_in[0];
  const float* h0   = (const float*)d_in[1];
  const float* W_in = (const float*)d_in[2];
  const float* b_in = (const float*)d_in[3];
  const float* W_hh = (const float*)d_in[4];
  const float* b_hh = (const float*)d_in[5];
  const float* W1   = (const float*)d_in[6];
  const float* b1   = (const float*)d_in[7];
  const float* W2   = (const float*)d_in[8];
  const float* b2   = (const float*)d_in[9];
  float* out = (float*)d_out;

  seq_kernel<<<NBLK, NTHR, 0, stream>>>(x, out, h0, W_in, b_in, W_hh, b_hh, W1, b1, W2, b2);
}

// Round 4
// 1381.682 us; speedup vs baseline: 1.3409x; 1.3409x over previous
//
#include <hip/hip_runtime.h>

typedef short bf16x8 __attribute__((ext_vector_type(8)));
typedef float f32x4  __attribute__((ext_vector_type(4)));

#define TSTEPS 1000
#define BATCH  512
#define HID    64
#define INPD   64
#define FEAT   128
#define KEEP   5
#define KH     320
#define ALPHA  0.2f
#define BB     2
#define NBLK   (BATCH/BB)   // 256
#define NTHR   512

#define MFMA(a,b,c) __builtin_amdgcn_mfma_f32_16x16x32_bf16(a, b, c, 0, 0, 0)

template<int P> struct IC { static constexpr int v = P; };

// split 4 f32 into bf16-hi (truncated) and bf16-lo (rounded residual), packed 2-per-u32
__device__ __forceinline__ void pack4(float x0, float x1, float x2, float x3,
                                      unsigned &h0, unsigned &h1,
                                      unsigned &l0, unsigned &l1) {
  unsigned a0 = __float_as_uint(x0), a1 = __float_as_uint(x1);
  unsigned a2 = __float_as_uint(x2), a3 = __float_as_uint(x3);
  h0 = __builtin_amdgcn_perm(a1, a0, 0x07060302u);   // {bf16(x1), bf16(x0)}
  h1 = __builtin_amdgcn_perm(a3, a2, 0x07060302u);
  float r0 = x0 - __uint_as_float(a0 & 0xFFFF0000u);
  float r1 = x1 - __uint_as_float(a1 & 0xFFFF0000u);
  float r2 = x2 - __uint_as_float(a2 & 0xFFFF0000u);
  float r3 = x3 - __uint_as_float(a3 & 0xFFFF0000u);
  asm("v_cvt_pk_bf16_f32 %0, %1, %2" : "=v"(l0) : "v"(r0), "v"(r1));
  asm("v_cvt_pk_bf16_f32 %0, %1, %2" : "=v"(l1) : "v"(r2), "v"(r3));
}

// load 8 consecutive f32 -> hi/lo bf16x8 fragments (elem i = k-offset i)
__device__ __forceinline__ void load_wfrag(const float* p, bf16x8 &hi, bf16x8 &lo) {
  float4 v0 = *(const float4*)p;
  float4 v1 = *(const float4*)(p + 4);
  int4 h4, l4;
  pack4(v0.x, v0.y, v0.z, v0.w, (unsigned&)h4.x, (unsigned&)h4.y, (unsigned&)l4.x, (unsigned&)l4.y);
  pack4(v1.x, v1.y, v1.z, v1.w, (unsigned&)h4.z, (unsigned&)h4.w, (unsigned&)l4.z, (unsigned&)l4.w);
  hi = __builtin_bit_cast(bf16x8, h4);
  lo = __builtin_bit_cast(bf16x8, l4);
}

// ---------------- xin = x @ W_in^T + b_in + b_hh -> io[t,b,h]  (proven round-2 kernel) ----------------
__global__ __launch_bounds__(512) void xin_kernel(const float* __restrict__ x,
                                                  const float* __restrict__ W_in,
                                                  const float* __restrict__ b_in,
                                                  const float* __restrict__ b_hh,
                                                  float* __restrict__ xin) {
  const int lane = threadIdx.x & 63;
  float wreg[64];
  const float4* wrow = (const float4*)(W_in + lane * INPD);
#pragma unroll
  for (int q = 0; q < 16; ++q) {
    float4 v = wrow[q];
    wreg[4*q+0] = v.x; wreg[4*q+1] = v.y; wreg[4*q+2] = v.z; wreg[4*q+3] = v.w;
  }
  const float bias = b_in[lane] + b_hh[lane];
  int wid = blockIdx.x * (blockDim.x >> 6) + (threadIdx.x >> 6);
  const int nw = gridDim.x * (blockDim.x >> 6);
  for (int tb = wid; tb < TSTEPS*BATCH; tb += nw) {
    const float* xp = x + (size_t)tb * INPD;
    float acc = bias;
#pragma unroll
    for (int i = 0; i < INPD; i += 4) {
      float4 xv = *(const float4*)(xp + i);
      acc = fmaf(xv.x, wreg[i+0], acc);
      acc = fmaf(xv.y, wreg[i+1], acc);
      acc = fmaf(xv.z, wreg[i+2], acc);
      acc = fmaf(xv.w, wreg[i+3], acc);
    }
    xin[(size_t)tb * HID + lane] = acc;
  }
}

// ---------------- persistent MFMA sequential kernel ----------------
// 256 blocks (1/CU) x 8 waves, BB=2. Weights + 5-slot hidden ring live in
// registers as MFMA fragments (bf16 hi/lo split, 3-product fp32-accurate).
// Per step: P1 all waves: MLP1 (30 mfma) + a relu/pack -> a_s | bar
//           P2 waves0-3: RNN (6 mfma)+xin -> h_obs; waves4-7: MLP2 (12 mfma) -> hm_s | bar
//           P3 waves0-3: h_t = mix, store io, pack -> B1lds | bar
__global__ __launch_bounds__(NTHR, 2) void seq_kernel(float* __restrict__ io,
                                                      const float* __restrict__ h0g,
                                                      const float* __restrict__ W_hh,
                                                      const float* __restrict__ W1,
                                                      const float* __restrict__ b1,
                                                      const float* __restrict__ W2,
                                                      const float* __restrict__ b2) {
  __shared__ __align__(16) short B1lds[2048];  // 4KB: new-h frag staging [(q*2+sp)][g][col16][i8]
  __shared__ __align__(16) short a_s[512];     // 1KB: relu(mlp1) bf16 [sp][col2][f128]
  __shared__ __align__(16) float hm_s[128];    // mlp2 out f32 [col2][h64]

  const int tid  = threadIdx.x;
  const int w    = tid >> 6;        // wave 0..7
  const int lane = tid & 63;
  const int q15  = lane & 15;       // A-row / B-col / C-col lane index
  const int g    = lane >> 4;       // 0..3
  const int b0   = blockIdx.x * BB;
  const int r0c  = 16*(w & 3) + 4*g;        // C-row base within 64 (waves mod 4)
  const int f0full = 16*w + 4*g;            // C-row base within 128 (MLP1)

  // per-thread LDS index constants
  const int aWH = q15*128 + f0full;         // a_s writer (hi), +256 for lo
  const int aR  = (q15&1)*128 + 8*g;        // a_s reader base (+kt*32, +256 lo)
  const int bWH = (r0c>>5)*1024 + ((r0c>>3)&3)*128 + q15*8 + (r0c&7);  // B1lds writer hi
  const int bRD = g*128 + q15*8;            // B1lds reader base (+ (q*2+sp)*512)

  const f32x4 vzero = {0.f, 0.f, 0.f, 0.f};

  // ---- weight fragments (one-time) ----
  bf16x8 w1h[10], w1l[10];
#pragma unroll
  for (int jt = 0; jt < 10; ++jt)
    load_wfrag(W1 + (size_t)(16*w + q15)*KH + jt*32 + 8*g, w1h[jt], w1l[jt]);

  bf16x8 wxh[4], wxl[4];   // waves0-3: W_hh (kt 0-1); waves4-7: W2 (kt 0-3)
  if (w < 4) {
#pragma unroll
    for (int kt = 0; kt < 2; ++kt)
      load_wfrag(W_hh + (size_t)(16*w + q15)*HID + kt*32 + 8*g, wxh[kt], wxl[kt]);
    wxh[2] = wxh[0]; wxl[2] = wxl[0]; wxh[3] = wxh[0]; wxl[3] = wxl[0]; // unused
  } else {
#pragma unroll
    for (int kt = 0; kt < 4; ++kt)
      load_wfrag(W2 + (size_t)(16*(w-4) + q15)*FEAT + kt*32 + 8*g, wxh[kt], wxl[kt]);
  }

  f32x4 b1r = *(const f32x4*)(b1 + f0full);           // bias rows f0full..+3
  f32x4 b2r = vzero;
  if (w >= 4) b2r = *(const f32x4*)(b2 + r0c);

  // ---- state init ----
  for (int i = tid; i < 1024; i += NTHR) ((unsigned*)B1lds)[i] = 0u;  // zero incl. cols 2-15
  __syncthreads();

  f32x4 hprev = vzero;
  if (w < 4 && q15 < 2)
    hprev = *(const f32x4*)(h0g + (size_t)(b0 + q15)*HID + r0c);

  if (w < 4) {   // stage h0 as the "newest" frag for t=0's RNN read (ring stays zero for MLP1: discarded t<5)
    unsigned i0_, i1_, i2_, i3_;
    pack4(hprev.x, hprev.y, hprev.z, hprev.w, i0_, i1_, i2_, i3_);
    if (q15 < 2) {
      *(uint2*)&B1lds[bWH]       = make_uint2(i0_, i1_);
      *(uint2*)&B1lds[bWH + 512] = make_uint2(i2_, i3_);
    }
  }

  bf16x8 rbh[KEEP][2], rbl[KEEP][2];   // hidden ring B-fragments, slot-major
  const bf16x8 z8 = {0,0,0,0,0,0,0,0};
#pragma unroll
  for (int s = 0; s < KEEP; ++s) {
    rbh[s][0] = z8; rbl[s][0] = z8; rbh[s][1] = z8; rbl[s][1] = z8;
  }
  __syncthreads();

  int t5 = 0;
  auto step = [&](auto pc) {
    constexpr int ph = decltype(pc)::v;
    constexpr int sN = (ph + 4) % 5;            // slot holding h_{t-1}
    const int t = t5 + ph;
    const size_t ioff = (size_t)t*(BATCH*HID) + (size_t)(b0 + q15)*HID + r0c;

    // prefetch xin (consumed in P2 by waves 0-3)
    float4 xf = make_float4(0.f, 0.f, 0.f, 0.f);
    if (w < 4 && q15 < 2) xf = *(const float4*)(io + ioff);

    // pull h_{t-1} fragments (staged in P3 of prev step / init)
    rbh[sN][0] = *(const bf16x8*)&B1lds[bRD];
    rbl[sN][0] = *(const bf16x8*)&B1lds[bRD + 512];
    rbh[sN][1] = *(const bf16x8*)&B1lds[bRD + 1024];
    rbl[sN][1] = *(const bf16x8*)&B1lds[bRD + 1536];

    // ---- P1: MLP1, K=320 over 5 slots x 2 ktiles, 3-product split ----
    f32x4 chh = vzero, chl = vzero, clh = vzero;
#pragma unroll
    for (int e = 1; e <= 5; ++e) {
      const int s = (sN + e) % 5;               // process sN last (freshest LDS read)
      const int r = ((s - ph) % 5 + 5) % 5;     // age rank of slot s at step t
#pragma unroll
      for (int q = 0; q < 2; ++q) {
        const int jt = 2*r + q;
        chh = MFMA(w1h[jt], rbh[s][q], chh);
        chl = MFMA(w1h[jt], rbl[s][q], chl);
        clh = MFMA(w1l[jt], rbh[s][q], clh);
      }
    }
    f32x4 apre = (chh + chl) + (clh + b1r);
    f32x4 av = __builtin_elementwise_max(apre, vzero);
    {
      unsigned p0, p1, p2, p3;
      pack4(av.x, av.y, av.z, av.w, p0, p1, p2, p3);
      if (q15 < 2) {
        *(uint2*)&a_s[aWH]       = make_uint2(p0, p1);
        *(uint2*)&a_s[aWH + 256] = make_uint2(p2, p3);
      }
    }
    __syncthreads();   // bar A: a_s ready; rb[sN] reads done

    // ---- P2 ----
    f32x4 hobs = vzero;
    if (w < 4) {
      f32x4 dhh = vzero, dhl = vzero, dlh = vzero;
#pragma unroll
      for (int q = 0; q < 2; ++q) {
        dhh = MFMA(wxh[q], rbh[sN][q], dhh);
        dhl = MFMA(wxh[q], rbl[sN][q], dhl);
        dlh = MFMA(wxl[q], rbh[sN][q], dlh);
      }
      f32x4 pre = (dhh + dhl) + dlh;
      pre.x += xf.x; pre.y += xf.y; pre.z += xf.z; pre.w += xf.w;   // xin includes biases
      f32x4 rl = __builtin_elementwise_max(pre, vzero);
      hobs = hprev * (1.f - ALPHA) + rl * ALPHA;
    } else {
      bf16x8 bh0 = *(const bf16x8*)&a_s[aR +  0];
      bf16x8 bh1 = *(const bf16x8*)&a_s[aR + 32];
      bf16x8 bh2 = *(const bf16x8*)&a_s[aR + 64];
      bf16x8 bh3 = *(const bf16x8*)&a_s[aR + 96];
      bf16x8 bl0 = *(const bf16x8*)&a_s[aR + 256];
      bf16x8 bl1 = *(const bf16x8*)&a_s[aR + 288];
      bf16x8 bl2 = *(const bf16x8*)&a_s[aR + 320];
      bf16x8 bl3 = *(const bf16x8*)&a_s[aR + 352];
      f32x4 ehh = vzero, ehl = vzero, elh = vzero;
      ehh = MFMA(wxh[0], bh0, ehh); ehl = MFMA(wxh[0], bl0, ehl); elh = MFMA(wxl[0], bh0, elh);
      ehh = MFMA(wxh[1], bh1, ehh); ehl = MFMA(wxh[1], bl1, ehl); elh = MFMA(wxl[1], bh1, elh);
      ehh = MFMA(wxh[2], bh2, ehh); ehl = MFMA(wxh[2], bl2, ehl); elh = MFMA(wxl[2], bh2, elh);
      ehh = MFMA(wxh[3], bh3, ehh); ehl = MFMA(wxh[3], bl3, ehl); elh = MFMA(wxl[3], bh3, elh);
      f32x4 hm = (ehh + ehl) + (elh + b2r);
      if (q15 < 2) *(f32x4*)&hm_s[q15*64 + r0c] = hm;
    }
    __syncthreads();   // bar B: hm_s ready

    // ---- P3: finalize h_t (waves 0-3) ----
    if (w < 4) {
      f32x4 hm = *(const f32x4*)&hm_s[(q15&1)*64 + r0c];
      f32x4 hnew = (t >= KEEP) ? ((hobs + hm) * 0.5f) : hobs;
      if (q15 < 2) {
        *(f32x4*)(io + ioff) = hnew;
        if (t == TSTEPS-1)
          *(f32x4*)(io + (size_t)TSTEPS*(BATCH*HID) + (size_t)(b0 + q15)*HID + r0c) = hnew;
      }
      unsigned n0, n1, n2, n3;
      pack4(hnew.x, hnew.y, hnew.z, hnew.w, n0, n1, n2, n3);
      if (q15 < 2) {
        *(uint2*)&B1lds[bWH]       = make_uint2(n0, n1);
        *(uint2*)&B1lds[bWH + 512] = make_uint2(n2, n3);
      }
      hprev = hnew;
    }
    __syncthreads();   // bar C: B1lds staged for next step
  };

  for (t5 = 0; t5 < TSTEPS; t5 += 5) {
    step(IC<0>{});
    step(IC<1>{});
    step(IC<2>{});
    step(IC<3>{});
    step(IC<4>{});
  }
}

extern "C" void kernel_launch(void* const* d_in, const int* in_sizes, int n_in,
                              void* d_out, int out_size, void* d_ws, size_t ws_size,
                              hipStream_t stream) {
  (void)in_sizes; (void)n_in; (void)out_size; (void)d_ws; (void)ws_size;
  const float* x    = (const float*)d_in[0];
  const float* h0   = (const float*)d_in[1];
  const float* W_in = (const float*)d_in[2];
  const float* b_in = (const float*)d_in[3];
  const float* W_hh = (const float*)d_in[4];
  const float* b_hh = (const float*)d_in[5];
  const float* W1   = (const float*)d_in[6];
  const float* b1   = (const float*)d_in[7];
  const float* W2   = (const float*)d_in[8];
  const float* b2   = (const float*)d_in[9];
  float* out = (float*)d_out;

  xin_kernel<<<2048, 512, 0, stream>>>(x, W_in, b_in, b_hh, out);
  seq_kernel<<<NBLK, NTHR, 0, stream>>>(out, h0, W_hh, W1, b1, W2, b2);
}